// Round 1
// baseline (269.390 us; speedup 1.0000x reference)
//
#include <hip/hip_runtime.h>
#include <hip/hip_bf16.h>

#define NB 16
#define NS 2048
#define NE 256
#define NOUT 256

typedef __attribute__((ext_vector_type(4))) float f32x4;
typedef __attribute__((ext_vector_type(8))) short s16x8;

__device__ __forceinline__ short bf16rn(float f) {
  unsigned u = __builtin_bit_cast(unsigned, f);
  u += 0x7FFFu + ((u >> 16) & 1u);
  return (short)(u >> 16);
}

// ---------- sq[b,s] = sum_e x^2 (f32, exact-ish) ----------
__global__ __launch_bounds__(256) void sq_kernel(const float* __restrict__ x,
                                                 float* __restrict__ sq) {
  int row = blockIdx.x * 4 + (threadIdx.x >> 6);  // one wave per row
  int lane = threadIdx.x & 63;
  f32x4 v = *(const f32x4*)(x + (size_t)row * NE + lane * 4);
  float s = v.x * v.x + v.y * v.y + v.z * v.z + v.w * v.w;
#pragma unroll
  for (int off = 32; off; off >>= 1) s += __shfl_xor(s, off);
  if (lane == 0) sq[row] = s;
}

// ---------- Gram pass: PASS=1 row sums r[s], PASS=2 col sums c[t] ----------
template <int PASS>
__global__ __launch_bounds__(256, 2) void gram_pass(
    const float* __restrict__ x, const float* __restrict__ sqg,
    const float* __restrict__ alpha_p, float* __restrict__ rws,
    float* __restrict__ cws) {
  __shared__ short ldsA[128 * 64];  // [row][k] bf16, XOR-swizzled
  __shared__ short ldsB[128 * 64];
  __shared__ float sqs[128];
  __shared__ float sqt[128];
  __shared__ float rinv[128];

  const int tid = threadIdx.x;
  const int bb = blockIdx.z;
  const int rowbase = blockIdx.y * 128;
  const int colbase = blockIdx.x * 128;
  const float* xb = x + (size_t)bb * NS * NE;

  if (tid < 128) {
    sqs[tid] = sqg[bb * NS + rowbase + tid];
    sqt[tid] = sqg[bb * NS + colbase + tid];
    if (PASS == 2) rinv[tid] = 1.0f / rws[bb * NS + rowbase + tid];
  }
  const float alpha = alpha_p[0];

  const int lane = tid & 63;
  const int wid = tid >> 6;
  const int wr = wid >> 1, wc = wid & 1;   // 2x2 waves, 64x64 each
  const int lrow = lane & 15, lq = lane >> 4;

  f32x4 acc[4][4];
#pragma unroll
  for (int m = 0; m < 4; ++m)
#pragma unroll
    for (int n = 0; n < 4; ++n) acc[m][n] = (f32x4){0.f, 0.f, 0.f, 0.f};

#pragma unroll 1
  for (int kt = 0; kt < 4; ++kt) {  // K = 256 in BK=64 tiles
    __syncthreads();
    // stage 128x64 bf16 tiles for A (rows=s) and B (rows=t); 16B chunks
#pragma unroll
    for (int j = 0; j < 4; ++j) {
      int q = tid + j * 256;       // 1024 chunks per tile
      int row = q >> 3, qi = q & 7;
      int sw = row * 128 + ((qi * 16) ^ ((row & 7) << 4));
      {
        const f32x4* src =
            (const f32x4*)(xb + (size_t)(rowbase + row) * NE + kt * 64 + qi * 8);
        f32x4 a0 = src[0], a1 = src[1];
        s16x8 p;
        p[0] = bf16rn(a0.x); p[1] = bf16rn(a0.y); p[2] = bf16rn(a0.z); p[3] = bf16rn(a0.w);
        p[4] = bf16rn(a1.x); p[5] = bf16rn(a1.y); p[6] = bf16rn(a1.z); p[7] = bf16rn(a1.w);
        *(s16x8*)((char*)ldsA + sw) = p;
      }
      {
        const f32x4* src =
            (const f32x4*)(xb + (size_t)(colbase + row) * NE + kt * 64 + qi * 8);
        f32x4 a0 = src[0], a1 = src[1];
        s16x8 p;
        p[0] = bf16rn(a0.x); p[1] = bf16rn(a0.y); p[2] = bf16rn(a0.z); p[3] = bf16rn(a0.w);
        p[4] = bf16rn(a1.x); p[5] = bf16rn(a1.y); p[6] = bf16rn(a1.z); p[7] = bf16rn(a1.w);
        *(s16x8*)((char*)ldsB + sw) = p;
      }
    }
    __syncthreads();
#pragma unroll
    for (int kk = 0; kk < 2; ++kk) {
      s16x8 af[4], bfv[4];
#pragma unroll
      for (int m = 0; m < 4; ++m) {
        int r = wr * 64 + m * 16 + lrow;
        int byt = r * 128 + (((kk * 64) + lq * 16) ^ ((r & 7) << 4));
        af[m] = *(const s16x8*)((const char*)ldsA + byt);
      }
#pragma unroll
      for (int n = 0; n < 4; ++n) {
        int r = wc * 64 + n * 16 + lrow;
        int byt = r * 128 + (((kk * 64) + lq * 16) ^ ((r & 7) << 4));
        bfv[n] = *(const s16x8*)((const char*)ldsB + byt);
      }
#pragma unroll
      for (int m = 0; m < 4; ++m)
#pragma unroll
        for (int n = 0; n < 4; ++n)
          acc[m][n] = __builtin_amdgcn_mfma_f32_16x16x32_bf16(af[m], bfv[n],
                                                              acc[m][n], 0, 0, 0);
    }
  }

  // epilogue: d2 -> w0 = exp(-alpha d2) -> exp(w0); reduce
  const float nal = -alpha;
  if (PASS == 1) {
#pragma unroll
    for (int m = 0; m < 4; ++m) {
#pragma unroll
      for (int j = 0; j < 4; ++j) {
        int rl = wr * 64 + m * 16 + lq * 4 + j;
        float ssq = sqs[rl];
        float rsum = 0.f;
#pragma unroll
        for (int n = 0; n < 4; ++n) {
          int cl = wc * 64 + n * 16 + lrow;
          float d2 = fmaxf(fmaf(-2.f, acc[m][n][j], ssq + sqt[cl]), 0.f);
          float w0 = __expf(nal * d2);
          rsum += __expf(w0);
        }
        rsum += __shfl_xor(rsum, 1);
        rsum += __shfl_xor(rsum, 2);
        rsum += __shfl_xor(rsum, 4);
        rsum += __shfl_xor(rsum, 8);
        if (lrow == 0) atomicAdd(&rws[bb * NS + rowbase + rl], rsum);
      }
    }
  } else {
    float csum[4] = {0.f, 0.f, 0.f, 0.f};
#pragma unroll
    for (int m = 0; m < 4; ++m) {
#pragma unroll
      for (int j = 0; j < 4; ++j) {
        int rl = wr * 64 + m * 16 + lq * 4 + j;
        float ssq = sqs[rl];
        float ri = rinv[rl];
#pragma unroll
        for (int n = 0; n < 4; ++n) {
          int cl = wc * 64 + n * 16 + lrow;
          float d2 = fmaxf(fmaf(-2.f, acc[m][n][j], ssq + sqt[cl]), 0.f);
          float w0 = __expf(nal * d2);
          csum[n] = fmaf(__expf(w0), ri, csum[n]);
        }
      }
    }
#pragma unroll
    for (int n = 0; n < 4; ++n) {
      float v = csum[n];
      v += __shfl_xor(v, 16);
      v += __shfl_xor(v, 32);
      if (lq == 0) atomicAdd(&cws[bb * NS + colbase + wc * 64 + n * 16 + lrow], v);
    }
  }
}

// ---------- pooled[b,e] = (1/S) sum_t c[b,t] x[b,t,e] ----------
__global__ __launch_bounds__(256) void pooled_kernel(const float* __restrict__ x,
                                                     const float* __restrict__ cws,
                                                     float* __restrict__ pooled) {
  int b = blockIdx.y;
  int t0 = blockIdx.x * 128;
  const float* xb = x + ((size_t)b * NS + t0) * NE;
  const float* cb = cws + b * NS + t0;
  float acc = 0.f;
#pragma unroll 4
  for (int t = 0; t < 128; ++t)
    acc = fmaf(cb[t], xb[(size_t)t * NE + threadIdx.x], acc);
  atomicAdd(&pooled[b * NE + threadIdx.x], acc * (1.0f / NS));
}

// ---------- out[b,o] = pooled[b,:] . W[o,:] + bias[o] ----------
__global__ __launch_bounds__(256) void out_kernel(const float* __restrict__ pooled,
                                                  const float* __restrict__ W,
                                                  const float* __restrict__ bias,
                                                  float* __restrict__ out) {
  __shared__ float pl[NE];
  int b = blockIdx.x, o = threadIdx.x;
  pl[o] = pooled[b * NE + o];
  __syncthreads();
  const f32x4* wr4 = (const f32x4*)(W + (size_t)o * NE);
  float acc = bias[o];
#pragma unroll 8
  for (int e = 0; e < 64; ++e) {
    f32x4 w4 = wr4[e];
    acc += pl[e * 4 + 0] * w4.x + pl[e * 4 + 1] * w4.y + pl[e * 4 + 2] * w4.z +
           pl[e * 4 + 3] * w4.w;
  }
  out[b * NOUT + o] = acc;
}

extern "C" void kernel_launch(void* const* d_in, const int* in_sizes, int n_in,
                              void* d_out, int out_size, void* d_ws, size_t ws_size,
                              hipStream_t stream) {
  const float* x = (const float*)d_in[0];
  const float* alpha = (const float*)d_in[1];
  const float* W = (const float*)d_in[2];
  const float* bias = (const float*)d_in[3];
  float* out = (float*)d_out;

  float* rws = (float*)d_ws;          // B*S
  float* cws = rws + NB * NS;         // B*S
  float* pooled = cws + NB * NS;      // B*E
  float* sq = pooled + NB * NE;       // B*S

  // zero r, c, pooled (contiguous); ws is re-poisoned 0xAA before every call
  hipMemsetAsync(rws, 0, (size_t)(2 * NB * NS + NB * NE) * sizeof(float), stream);

  sq_kernel<<<NB * NS / 4, 256, 0, stream>>>(x, sq);
  gram_pass<1><<<dim3(16, 16, NB), 256, 0, stream>>>(x, sq, alpha, rws, cws);
  gram_pass<2><<<dim3(16, 16, NB), 256, 0, stream>>>(x, sq, alpha, rws, cws);
  pooled_kernel<<<dim3(16, NB), 256, 0, stream>>>(x, cws, pooled);
  out_kernel<<<NB, 256, 0, stream>>>(pooled, W, bias, out);
}

// Round 2
// 157.752 us; speedup vs baseline: 1.7077x; 1.7077x over previous
//
#include <hip/hip_runtime.h>
#include <hip/hip_bf16.h>

#define NB 16
#define NS 2048
#define NE 256
#define NOUT 256
#define TRI 136  // 16*17/2 upper-triangle tiles per batch

typedef __attribute__((ext_vector_type(4))) float f32x4;
typedef __attribute__((ext_vector_type(8))) short s16x8;
typedef __attribute__((ext_vector_type(4))) short s16x4;
typedef unsigned int u32;

__device__ __forceinline__ short bf16rn(float f) {
  unsigned u = __builtin_bit_cast(unsigned, f);
  u += 0x7FFFu + ((u >> 16) & 1u);
  return (short)(u >> 16);
}
__device__ __forceinline__ float bf16f(short s) {
  unsigned u = ((unsigned)(unsigned short)s) << 16;
  return __builtin_bit_cast(float, u);
}
__device__ __forceinline__ void gld_lds16(const void* g, void* l) {
  __builtin_amdgcn_global_load_lds(
      (const __attribute__((address_space(1))) u32*)g,
      (__attribute__((address_space(3))) u32*)l, 16, 0, 0);
}

// ---------- prep: x f32 -> xbf bf16 (row-major) + sq[b,s] ----------
__global__ __launch_bounds__(256) void prep_kernel(const float* __restrict__ x,
                                                   short* __restrict__ xbf,
                                                   float* __restrict__ sq) {
  int row = blockIdx.x * 4 + (threadIdx.x >> 6);  // one wave per row
  int lane = threadIdx.x & 63;
  f32x4 v = *(const f32x4*)(x + (size_t)row * NE + lane * 4);
  s16x4 p;
  p[0] = bf16rn(v.x); p[1] = bf16rn(v.y); p[2] = bf16rn(v.z); p[3] = bf16rn(v.w);
  *(s16x4*)(xbf + (size_t)row * NE + lane * 4) = p;
  float s = v.x * v.x + v.y * v.y + v.z * v.z + v.w * v.w;
#pragma unroll
  for (int off = 32; off; off >>= 1) s += __shfl_xor(s, off);
  if (lane == 0) sq[row] = s;
}

// ---------- gram pass 1 (upper triangle): r[s] = sum_t exp(w0) ----------
__global__ __launch_bounds__(256, 4) void gram1(
    const short* __restrict__ xbf, const float* __restrict__ sqg,
    const float* __restrict__ alpha_p, float* __restrict__ rws,
    int* __restrict__ flags) {
  __shared__ short ldsA[128 * 64];
  __shared__ short ldsB[128 * 64];
  __shared__ float sqs[128];
  __shared__ float sqt[128];

  const int tid = threadIdx.x;
  // XCD-chunked swizzle: 2176 = 8 * 272 -> each XCD gets 2 batches' triangles
  int bid = blockIdx.x;
  int nbid = (bid & 7) * 272 + (bid >> 3);
  int bb = nbid / 136;
  int t = nbid - bb * 136;
  int by = 0;
  while (t >= 16 - by) { t -= 16 - by; ++by; }
  int bx = by + t;
  const int rowbase = by * 128, colbase = bx * 128;
  const short* xb = xbf + (size_t)bb * NS * NE;

  if (tid < 128) {
    sqs[tid] = sqg[bb * NS + rowbase + tid];
    sqt[tid] = sqg[bb * NS + colbase + tid];
  }
  const float alpha = alpha_p[0];

  const int lane = tid & 63;
  const int wid = tid >> 6;
  const int wr = wid >> 1, wc = wid & 1;
  const int lrow = lane & 15, lq = lane >> 4;

  // staging addresses: swizzled global source, linear LDS dest
  const int boff = ((lane & 7) * 16) ^ ((lane >> 3) << 4);
  const char* gA = (const char*)xb + (size_t)(rowbase + wid * 32 + (lane >> 3)) * 512 + boff;
  const char* gB = (const char*)xb + (size_t)(colbase + wid * 32 + (lane >> 3)) * 512 + boff;
  char* lA = (char*)ldsA + wid * 32 * 128 + lane * 16;
  char* lB = (char*)ldsB + wid * 32 * 128 + lane * 16;

  f32x4 acc[4][4];
#pragma unroll
  for (int m = 0; m < 4; ++m)
#pragma unroll
    for (int n = 0; n < 4; ++n) acc[m][n] = (f32x4){0.f, 0.f, 0.f, 0.f};

#pragma unroll 1
  for (int kt = 0; kt < 4; ++kt) {
    __syncthreads();
#pragma unroll
    for (int i = 0; i < 4; ++i) {
      gld_lds16(gA + (size_t)kt * 128 + i * 4096, lA + i * 1024);
      gld_lds16(gB + (size_t)kt * 128 + i * 4096, lB + i * 1024);
    }
    __syncthreads();
#pragma unroll
    for (int kk = 0; kk < 2; ++kk) {
      s16x8 af[4], bfv[4];
#pragma unroll
      for (int m = 0; m < 4; ++m) {
        int r = wr * 64 + m * 16 + lrow;
        int byt = r * 128 + (((kk * 64) + lq * 16) ^ ((r & 7) << 4));
        af[m] = *(const s16x8*)((const char*)ldsA + byt);
      }
#pragma unroll
      for (int n = 0; n < 4; ++n) {
        int r = wc * 64 + n * 16 + lrow;
        int byt = r * 128 + (((kk * 64) + lq * 16) ^ ((r & 7) << 4));
        bfv[n] = *(const s16x8*)((const char*)ldsB + byt);
      }
#pragma unroll
      for (int m = 0; m < 4; ++m)
#pragma unroll
        for (int n = 0; n < 4; ++n)
          acc[m][n] = __builtin_amdgcn_mfma_f32_16x16x32_bf16(af[m], bfv[n],
                                                              acc[m][n], 0, 0, 0);
    }
  }

  // epilogue
  const float nal = -alpha;
  const float thresh = 17.328680f / alpha;  // 25*ln2/alpha: w0 < 2^-25 -> exp(w0)==1.0f
  float ssq[4][4], sqtl[4];
#pragma unroll
  for (int m = 0; m < 4; ++m)
#pragma unroll
    for (int j = 0; j < 4; ++j) ssq[m][j] = sqs[wr * 64 + m * 16 + lq * 4 + j];
#pragma unroll
  for (int n = 0; n < 4; ++n) sqtl[n] = sqt[wc * 64 + n * 16 + lrow];

  float mind2 = 3.4e38f;
#pragma unroll
  for (int m = 0; m < 4; ++m)
#pragma unroll
    for (int n = 0; n < 4; ++n)
#pragma unroll
      for (int j = 0; j < 4; ++j)
        mind2 = fminf(mind2, fmaf(-2.f, acc[m][n][j], ssq[m][j] + sqtl[n]));
  const bool skip = __all(mind2 > thresh);

  if (skip) {
    // every exp(w0) == 1.0f exactly: rows += 64, (if off-diag) cols += 64
    if (lrow == 0) {
#pragma unroll
      for (int m = 0; m < 4; ++m)
#pragma unroll
        for (int j = 0; j < 4; ++j)
          atomicAdd(&rws[bb * NS + rowbase + wr * 64 + m * 16 + lq * 4 + j], 64.0f);
    }
    if (by != bx && lq == 0) {
#pragma unroll
      for (int n = 0; n < 4; ++n)
        atomicAdd(&rws[bb * NS + colbase + wc * 64 + n * 16 + lrow], 64.0f);
    }
  } else {
    if (lane == 0) {
      atomicOr(&flags[bb * 256 + by * 16 + bx], 1);
      if (by != bx) atomicOr(&flags[bb * 256 + bx * 16 + by], 1);
    }
    float csum[4] = {0.f, 0.f, 0.f, 0.f};
#pragma unroll
    for (int m = 0; m < 4; ++m) {
#pragma unroll
      for (int j = 0; j < 4; ++j) {
        float rsum = 0.f;
#pragma unroll
        for (int n = 0; n < 4; ++n) {
          float d2 = fmaxf(fmaf(-2.f, acc[m][n][j], ssq[m][j] + sqtl[n]), 0.f);
          float w = __expf(__expf(nal * d2));
          rsum += w;
          csum[n] += w;
        }
        rsum += __shfl_xor(rsum, 1);
        rsum += __shfl_xor(rsum, 2);
        rsum += __shfl_xor(rsum, 4);
        rsum += __shfl_xor(rsum, 8);
        if (lrow == 0)
          atomicAdd(&rws[bb * NS + rowbase + wr * 64 + m * 16 + lq * 4 + j], rsum);
      }
    }
    if (by != bx) {
#pragma unroll
      for (int n = 0; n < 4; ++n) {
        float v = csum[n];
        v += __shfl_xor(v, 16);
        v += __shfl_xor(v, 32);
        if (lq == 0)
          atomicAdd(&rws[bb * NS + colbase + wc * 64 + n * 16 + lrow], v);
      }
    }
  }
}

// ---------- rinv: rinv_g = 1/r; rbsum[b,blk] = sum over 128 rows ----------
__global__ __launch_bounds__(128) void rinv_kernel(const float* __restrict__ rws,
                                                   float* __restrict__ rinv_g,
                                                   float* __restrict__ rbsum) {
  __shared__ float ws2[2];
  int i = blockIdx.x * 128 + threadIdx.x;
  float inv = 1.0f / rws[i];
  rinv_g[i] = inv;
  float s = inv;
#pragma unroll
  for (int off = 32; off; off >>= 1) s += __shfl_xor(s, off);
  if ((threadIdx.x & 63) == 0) ws2[threadIdx.x >> 6] = s;
  __syncthreads();
  if (threadIdx.x == 0) rbsum[blockIdx.x] = ws2[0] + ws2[1];
}

// ---------- gram pass 2: c[t] = sum_s exp(w0)/r[s]; skip via flags ----------
__global__ __launch_bounds__(256, 4) void gram2(
    const short* __restrict__ xbf, const float* __restrict__ sqg,
    const float* __restrict__ alpha_p, const float* __restrict__ rinv_g,
    const float* __restrict__ rbsum, const int* __restrict__ flags,
    float* __restrict__ cws) {
  __shared__ short ldsA[128 * 64];
  __shared__ short ldsB[128 * 64];
  __shared__ float sqs[128];
  __shared__ float sqt[128];
  __shared__ float rinvs[128];

  const int tid = threadIdx.x;
  int bid = blockIdx.x;  // 4096 = 8 * 512
  int nbid = (bid & 7) * 512 + (bid >> 3);
  int bb = nbid >> 8;
  int rr = nbid & 255;
  int by = rr >> 4, bx = rr & 15;
  const int rowbase = by * 128, colbase = bx * 128;

  if (flags[bb * 256 + by * 16 + bx] == 0) {
    // all exp(w0)==1: column contribution = sum of 1/r over this row block
    if (tid < 128) atomicAdd(&cws[bb * NS + colbase + tid], rbsum[bb * 16 + by]);
    return;
  }

  const short* xb = xbf + (size_t)bb * NS * NE;
  if (tid < 128) {
    sqs[tid] = sqg[bb * NS + rowbase + tid];
    sqt[tid] = sqg[bb * NS + colbase + tid];
    rinvs[tid] = rinv_g[bb * NS + rowbase + tid];
  }
  const float alpha = alpha_p[0];

  const int lane = tid & 63;
  const int wid = tid >> 6;
  const int wr = wid >> 1, wc = wid & 1;
  const int lrow = lane & 15, lq = lane >> 4;

  const int boff = ((lane & 7) * 16) ^ ((lane >> 3) << 4);
  const char* gA = (const char*)xb + (size_t)(rowbase + wid * 32 + (lane >> 3)) * 512 + boff;
  const char* gB = (const char*)xb + (size_t)(colbase + wid * 32 + (lane >> 3)) * 512 + boff;
  char* lA = (char*)ldsA + wid * 32 * 128 + lane * 16;
  char* lB = (char*)ldsB + wid * 32 * 128 + lane * 16;

  f32x4 acc[4][4];
#pragma unroll
  for (int m = 0; m < 4; ++m)
#pragma unroll
    for (int n = 0; n < 4; ++n) acc[m][n] = (f32x4){0.f, 0.f, 0.f, 0.f};

#pragma unroll 1
  for (int kt = 0; kt < 4; ++kt) {
    __syncthreads();
#pragma unroll
    for (int i = 0; i < 4; ++i) {
      gld_lds16(gA + (size_t)kt * 128 + i * 4096, lA + i * 1024);
      gld_lds16(gB + (size_t)kt * 128 + i * 4096, lB + i * 1024);
    }
    __syncthreads();
#pragma unroll
    for (int kk = 0; kk < 2; ++kk) {
      s16x8 af[4], bfv[4];
#pragma unroll
      for (int m = 0; m < 4; ++m) {
        int r = wr * 64 + m * 16 + lrow;
        int byt = r * 128 + (((kk * 64) + lq * 16) ^ ((r & 7) << 4));
        af[m] = *(const s16x8*)((const char*)ldsA + byt);
      }
#pragma unroll
      for (int n = 0; n < 4; ++n) {
        int r = wc * 64 + n * 16 + lrow;
        int byt = r * 128 + (((kk * 64) + lq * 16) ^ ((r & 7) << 4));
        bfv[n] = *(const s16x8*)((const char*)ldsB + byt);
      }
#pragma unroll
      for (int m = 0; m < 4; ++m)
#pragma unroll
        for (int n = 0; n < 4; ++n)
          acc[m][n] = __builtin_amdgcn_mfma_f32_16x16x32_bf16(af[m], bfv[n],
                                                              acc[m][n], 0, 0, 0);
    }
  }

  const float nal = -alpha;
  float csum[4] = {0.f, 0.f, 0.f, 0.f};
#pragma unroll
  for (int m = 0; m < 4; ++m) {
#pragma unroll
    for (int j = 0; j < 4; ++j) {
      int rl = wr * 64 + m * 16 + lq * 4 + j;
      float ssq = sqs[rl];
      float ri = rinvs[rl];
#pragma unroll
      for (int n = 0; n < 4; ++n) {
        int cl = wc * 64 + n * 16 + lrow;
        float d2 = fmaxf(fmaf(-2.f, acc[m][n][j], ssq + sqt[cl]), 0.f);
        float w0 = __expf(nal * d2);
        csum[n] = fmaf(__expf(w0), ri, csum[n]);
      }
    }
  }
#pragma unroll
  for (int n = 0; n < 4; ++n) {
    float v = csum[n];
    v += __shfl_xor(v, 16);
    v += __shfl_xor(v, 32);
    if (lq == 0) atomicAdd(&cws[bb * NS + colbase + wc * 64 + n * 16 + lrow], v);
  }
}

// ---------- pooled[b,e] = (1/S) sum_t c[b,t] x[b,t,e] (bf16 x) ----------
__global__ __launch_bounds__(256) void pooled_kernel(const short* __restrict__ xbf,
                                                     const float* __restrict__ cws,
                                                     float* __restrict__ pooled) {
  int b = blockIdx.y;
  int t0 = blockIdx.x * 128;
  const short* xb = xbf + ((size_t)b * NS + t0) * NE;
  const float* cb = cws + b * NS + t0;
  float acc = 0.f;
#pragma unroll 4
  for (int t = 0; t < 128; ++t)
    acc = fmaf(cb[t], bf16f(xb[(size_t)t * NE + threadIdx.x]), acc);
  atomicAdd(&pooled[b * NE + threadIdx.x], acc * (1.0f / NS));
}

// ---------- out[b,o] = pooled[b,:] . W[o,:] + bias[o] ----------
__global__ __launch_bounds__(256) void out_kernel(const float* __restrict__ pooled,
                                                  const float* __restrict__ W,
                                                  const float* __restrict__ bias,
                                                  float* __restrict__ out) {
  __shared__ float pl[NE];
  int b = blockIdx.x, o = threadIdx.x;
  pl[o] = pooled[b * NE + o];
  __syncthreads();
  const f32x4* wr4 = (const f32x4*)(W + (size_t)o * NE);
  float acc = bias[o];
#pragma unroll 8
  for (int e = 0; e < 64; ++e) {
    f32x4 w4 = wr4[e];
    acc += pl[e * 4 + 0] * w4.x + pl[e * 4 + 1] * w4.y + pl[e * 4 + 2] * w4.z +
           pl[e * 4 + 3] * w4.w;
  }
  out[b * NOUT + o] = acc;
}

extern "C" void kernel_launch(void* const* d_in, const int* in_sizes, int n_in,
                              void* d_out, int out_size, void* d_ws, size_t ws_size,
                              hipStream_t stream) {
  const float* x = (const float*)d_in[0];
  const float* alpha = (const float*)d_in[1];
  const float* W = (const float*)d_in[2];
  const float* bias = (const float*)d_in[3];
  float* out = (float*)d_out;

  float* rws = (float*)d_ws;                 // NB*NS
  float* cws = rws + NB * NS;                // NB*NS
  float* pooled = cws + NB * NS;             // NB*NE
  int* flags = (int*)(pooled + NB * NE);     // NB*256
  float* sq = (float*)(flags + NB * 256);    // NB*NS
  float* rinv_g = sq + NB * NS;              // NB*NS
  float* rbsum = rinv_g + NB * NS;           // NB*16
  short* xbf = (short*)(rbsum + NB * 16);    // NB*NS*NE bf16

  // zero rws, cws, pooled, flags (contiguous)
  hipMemsetAsync(rws, 0,
                 (size_t)(2 * NB * NS + NB * NE + NB * 256) * sizeof(float),
                 stream);

  prep_kernel<<<NB * NS / 4, 256, 0, stream>>>(x, xbf, sq);
  gram1<<<NB * TRI, 256, 0, stream>>>(xbf, sq, alpha, rws, flags);
  rinv_kernel<<<NB * 16, 128, 0, stream>>>(rws, rinv_g, rbsum);
  gram2<<<NB * 256, 256, 0, stream>>>(xbf, sq, alpha, rinv_g, rbsum, flags, cws);
  pooled_kernel<<<dim3(16, NB), 256, 0, stream>>>(xbf, cws, pooled);
  out_kernel<<<NB, 256, 0, stream>>>(pooled, W, bias, out);
}